// Round 4
// baseline (737.490 us; speedup 1.0000x reference)
//
#include <hip/hip_runtime.h>

#define DIM 40
#define NSTEP 100

// Out-of-place Lorenz96 RHS: k = (x_{i+1} - x_{i-2})*x_{i-1} - x_i + F
__device__ __forceinline__ void l96(const float* __restrict__ x, float* __restrict__ k) {
#pragma unroll
    for (int i = 0; i < DIM; ++i) {
        const int ip1 = (i + 1) % DIM;
        const int im2 = (i + DIM - 2) % DIM;
        const int im1 = (i + DIM - 1) % DIM;
        k[i] = fmaf(x[ip1] - x[im2], x[im1], 8.0f - x[i]);
    }
}

// In-place Lorenz96 RHS: a <- f(a). Rolling window keeps pre-overwrite
// neighbor values; under full unroll prev1/prev2 are pure SSA renames.
__device__ __forceinline__ void l96_inplace(float* a) {
    const float a0 = a[0];     // i=39 needs original a[0] as its +1 neighbor
    float prev2 = a[DIM - 2];  // original a[i-2]
    float prev1 = a[DIM - 1];  // original a[i-1]
#pragma unroll
    for (int i = 0; i < DIM; ++i) {
        const float ip1 = (i < DIM - 1) ? a[i + 1] : a0;
        const float old = a[i];
        a[i] = fmaf(ip1 - prev2, prev1, 8.0f - old);
        prev2 = prev1;
        prev1 = old;
    }
}

// 3-array RK4(3/8) via the (p,q) reparameterization:
//   p = x - dt/3*k1, q = x + dt*k1
//   a2  = (p+q)/2                      (3p+q = 4x, q-p = 4dt/3*k1 -> exact)
//   acc = 21/32*p + 11/32*q + 3dt/8*k2 (= x + dt/8*k1 + 3dt/8*k2, exact consts)
//   a3  = p + dt*k2,  b = q - dt*k2    (b = x + dt*(k1-k2))
//   a4  = b + dt*k3;  x' = acc + 3dt/8*k3 + dt/8*k4
// Peak liveness: 120 floats (3 live arrays in every RHS-eval window), down
// from 160 in the 4-array form. Rounds 2-3 showed the allocator parks any
// live set it won't hold in arch VGPRs as VALU copy bloat (43e9 issued
// lane-ops vs 24e9 algorithmic) regardless of the budget knob -> the only
// fix is real liveness reduction.
__global__ void __launch_bounds__(256)
__attribute__((amdgpu_waves_per_eu(3, 3)))
lorenz96_rk4_kernel(const float* __restrict__ in,
                    float* __restrict__ out,
                    int batch) {
    const int row = blockIdx.x * blockDim.x + threadIdx.x;
    if (row >= batch) return;

    const float4* __restrict__ src = (const float4*)(in + (size_t)row * DIM);
    float X[DIM];  // x -> p -> a3 -> k3 -> x'
    float W[DIM];  // k1 -> q -> b -> a4 -> k4
    float A[DIM];  // acc (born after k2)
    float S[DIM];  // a2 -> k2 (short-lived)
#pragma unroll
    for (int i = 0; i < DIM / 4; ++i) {
        float4 v = src[i];
        X[4 * i + 0] = v.x;
        X[4 * i + 1] = v.y;
        X[4 * i + 2] = v.z;
        X[4 * i + 3] = v.w;
    }

    const float dt  = 0.01f;
    const float dt3 = dt * (1.0f / 3.0f);  // dt/3
    const float dt8 = dt * 0.125f;         // dt/8
    const float th  = 3.0f * dt8;          // 3dt/8

#pragma unroll 1
    for (int s = 0; s < NSTEP; ++s) {
        // k1 = f(x)                                  [live: X(x), W(k1) = 80]
        l96(X, W);

        // p = x - dt/3*k1 ; q = x + dt*k1 ; a2 = (p+q)/2
#pragma unroll
        for (int i = 0; i < DIM; ++i) {
            const float xi = X[i], ki = W[i];
            const float p = fmaf(-dt3, ki, xi);
            const float q = fmaf(dt, ki, xi);
            X[i] = p;
            W[i] = q;
            S[i] = 0.5f * (p + q);
        }

        // k2 = f(a2)  (in place: S)                  [live: X(p), W(q), S = 120]
        l96_inplace(S);

        // acc = 21/32*p + 11/32*q + 3dt/8*k2 ; a3 = p + dt*k2 ; b = q - dt*k2
#pragma unroll
        for (int i = 0; i < DIM; ++i) {
            const float k2 = S[i];
            const float p = X[i], q = W[i];
            A[i] = fmaf(th, k2, fmaf(0.34375f, q, 0.65625f * p));
            X[i] = fmaf(dt, k2, p);    // a3
            W[i] = fmaf(-dt, k2, q);   // b
        }

        // k3 = f(a3)  (in place: X)                  [live: A, W(b), X = 120]
        l96_inplace(X);

        // acc += 3dt/8*k3 ; a4 = b + dt*k3
#pragma unroll
        for (int i = 0; i < DIM; ++i) {
            A[i] = fmaf(th, X[i], A[i]);
            W[i] = fmaf(dt, X[i], W[i]);
        }

        // k4 = f(a4)  (in place: W)                  [live: A, W = 80]
        l96_inplace(W);

        // x' = acc + dt/8*k4
#pragma unroll
        for (int i = 0; i < DIM; ++i) X[i] = fmaf(dt8, W[i], A[i]);
    }

    float4* __restrict__ dst = (float4*)(out + (size_t)row * DIM);
#pragma unroll
    for (int i = 0; i < DIM / 4; ++i) {
        float4 v;
        v.x = X[4 * i + 0];
        v.y = X[4 * i + 1];
        v.z = X[4 * i + 2];
        v.w = X[4 * i + 3];
        dst[i] = v;
    }
}

extern "C" void kernel_launch(void* const* d_in, const int* in_sizes, int n_in,
                              void* d_out, int out_size, void* d_ws, size_t ws_size,
                              hipStream_t stream) {
    const float* x = (const float*)d_in[0];
    float* out = (float*)d_out;
    const int batch = in_sizes[0] / DIM;  // 262144
    const int block = 256;
    const int grid = (batch + block - 1) / block;
    lorenz96_rk4_kernel<<<grid, block, 0, stream>>>(x, out, batch);
}

// Round 5
// 626.433 us; speedup vs baseline: 1.1773x; 1.1773x over previous
//
#include <hip/hip_runtime.h>

#define NSTEP 100
#define LP 10  // elements per lane; 4 lanes (one quad) per 40-dim row

// DPP quad_perm ring rotation. quad_perm [p0,p1,p2,p3]: new lane i gets old
// lane p_i within its 4-lane quad. Lorenz96's cyclic ring maps exactly onto
// the quad ring: the mod-4 wrap implements the mod-40 wrap.
__device__ __forceinline__ float dpp_prev(float v) {  // from lane (sub-1)&3: p=[3,0,1,2]
    return __int_as_float(__builtin_amdgcn_mov_dpp(__float_as_int(v), 0x93, 0xf, 0xf, true));
}
__device__ __forceinline__ float dpp_next(float v) {  // from lane (sub+1)&3: p=[1,2,3,0]
    return __int_as_float(__builtin_amdgcn_mov_dpp(__float_as_int(v), 0x39, 0xf, 0xf, true));
}

// k = f(a) over this lane's 10-element segment, halos via DPP.
// Global element m = sub*10 + j: needs a[m+1], a[m-1], a[m-2] (cyclic).
__device__ __forceinline__ void l96_seg(const float* __restrict__ a, float* __restrict__ k) {
    const float hm2 = dpp_prev(a[LP - 2]);  // a[m-2] for j=0
    const float hm1 = dpp_prev(a[LP - 1]);  // a[m-1] for j=0 (= a[m-2] for j=1)
    const float hp1 = dpp_next(a[0]);       // a[m+1] for j=9
    k[0] = fmaf(a[1] - hm2, hm1, 8.0f - a[0]);
    k[1] = fmaf(a[2] - hm1, a[0], 8.0f - a[1]);
#pragma unroll
    for (int j = 2; j < LP - 1; ++j)
        k[j] = fmaf(a[j + 1] - a[j - 2], a[j - 1], 8.0f - a[j]);
    k[LP - 1] = fmaf(hp1 - a[LP - 3], a[LP - 2], 8.0f - a[LP - 1]);
}

// In-place variant: capture halos first (cross-lane values are read at the
// DPP instruction, before any lane overwrites), then rolling window.
__device__ __forceinline__ void l96_seg_inplace(float* a) {
    const float hp1 = dpp_next(a[0]);
    float prev2 = dpp_prev(a[LP - 2]);
    float prev1 = dpp_prev(a[LP - 1]);
#pragma unroll
    for (int j = 0; j < LP; ++j) {
        const float ip1 = (j < LP - 1) ? a[j + 1] : hp1;
        const float old = a[j];
        a[j] = fmaf(ip1 - prev2, prev1, 8.0f - old);
        prev2 = prev1;
        prev1 = old;
    }
}

// Round-2 RK4(3/8) flow (bit-identical fmaf sequence per element, absmax
// must reproduce 0.0625), distributed 4 lanes/row. Per-thread live set:
// 4 arrays x 10 = 40 floats + temps (~60 VGPRs) — far below the ~100-float
// threshold where rounds 1-4 showed the allocator generating 1.8x VALU bloat
// regardless of waves_per_eu/launch_bounds knobs.
__global__ void __launch_bounds__(256)
lorenz96_rk4_kernel(const float* __restrict__ in,
                    float* __restrict__ out,
                    int batch) {
    const int gtid = blockIdx.x * blockDim.x + threadIdx.x;
    const int row = gtid >> 2;
    const int sub = gtid & 3;
    if (row >= batch) return;

    // This lane's 10-float segment, float2 (8B) loads: offset sub*10 is even.
    const float2* __restrict__ src = (const float2*)(in + (size_t)row * 40 + sub * LP);
    float X[LP];  // x  -> b  -> a4 -> k4 -> x'
    float W[LP];  // k1 -> u  -> a3 -> k3
    float A[LP];  // acc
    float S[LP];  // a2 -> k2
#pragma unroll
    for (int i = 0; i < LP / 2; ++i) {
        float2 v = src[i];
        X[2 * i + 0] = v.x;
        X[2 * i + 1] = v.y;
    }

    const float dt  = 0.01f;
    const float dt3 = dt * (1.0f / 3.0f);  // dt/3
    const float dt8 = dt * 0.125f;         // dt/8
    const float th  = 3.0f * dt8;          // 3dt/8

#pragma unroll 1
    for (int s = 0; s < NSTEP; ++s) {
        // k1 = f(x)
        l96_seg(X, W);

        // u = dt/3*k1 ; acc = x + 0.375*u ; a2 = x + u
#pragma unroll
        for (int i = 0; i < LP; ++i) {
            W[i] = dt3 * W[i];
            A[i] = fmaf(0.375f, W[i], X[i]);
            S[i] = X[i] + W[i];
        }

        // k2 = f(a2)
        l96_seg_inplace(S);

        // acc += 3dt/8*k2 ; a3 = (x-u) + dt*k2 ; b = (x+3u) - dt*k2
#pragma unroll
        for (int i = 0; i < LP; ++i) {
            A[i] = fmaf(th, S[i], A[i]);
            const float t = X[i] - W[i];
            X[i] = fmaf(-dt, S[i], fmaf(3.0f, W[i], X[i]));  // b
            W[i] = fmaf(dt, S[i], t);                        // a3
        }

        // k3 = f(a3)
        l96_seg_inplace(W);

        // acc += 3dt/8*k3 ; a4 = b + dt*k3
#pragma unroll
        for (int i = 0; i < LP; ++i) {
            A[i] = fmaf(th, W[i], A[i]);
            X[i] = fmaf(dt, W[i], X[i]);
        }

        // k4 = f(a4)
        l96_seg_inplace(X);

        // x' = acc + dt/8*k4
#pragma unroll
        for (int i = 0; i < LP; ++i) X[i] = fmaf(dt8, X[i], A[i]);
    }

    float2* __restrict__ dst = (float2*)(out + (size_t)row * 40 + sub * LP);
#pragma unroll
    for (int i = 0; i < LP / 2; ++i) {
        float2 v;
        v.x = X[2 * i + 0];
        v.y = X[2 * i + 1];
        dst[i] = v;
    }
}

extern "C" void kernel_launch(void* const* d_in, const int* in_sizes, int n_in,
                              void* d_out, int out_size, void* d_ws, size_t ws_size,
                              hipStream_t stream) {
    const float* x = (const float*)d_in[0];
    float* out = (float*)d_out;
    const int batch = in_sizes[0] / 40;  // 262144
    const int block = 256;
    const long long threads = (long long)batch * 4;  // 4 lanes per row
    const int grid = (int)((threads + block - 1) / block);
    lorenz96_rk4_kernel<<<grid, block, 0, stream>>>(x, out, batch);
}

// Round 6
// 479.544 us; speedup vs baseline: 1.5379x; 1.3063x over previous
//
#include <hip/hip_runtime.h>

#define NSTEP 100
#define LP 10  // elements per lane; 4 lanes (one quad) per 40-dim ring

// Packed pair: component .x = row0, .y = row1 of a row-pair.
typedef float v2 __attribute__((ext_vector_type(2)));

__device__ __forceinline__ v2 sp(float s) { v2 r = {s, s}; return r; }
__device__ __forceinline__ v2 vfma(v2 a, v2 b, v2 c) { return __builtin_elementwise_fma(a, b, c); }

// DPP quad_perm ring rotation, componentwise (DPP is 32-bit).
__device__ __forceinline__ float dppf_prev(float v) {  // from lane (sub-1)&3
    return __int_as_float(__builtin_amdgcn_mov_dpp(__float_as_int(v), 0x93, 0xf, 0xf, true));
}
__device__ __forceinline__ float dppf_next(float v) {  // from lane (sub+1)&3
    return __int_as_float(__builtin_amdgcn_mov_dpp(__float_as_int(v), 0x39, 0xf, 0xf, true));
}
__device__ __forceinline__ v2 dpp_prev(v2 v) { v2 r; r.x = dppf_prev(v.x); r.y = dppf_prev(v.y); return r; }
__device__ __forceinline__ v2 dpp_next(v2 v) { v2 r; r.x = dppf_next(v.x); r.y = dppf_next(v.y); return r; }

// k = f(a) over this lane's 10-element packed segment, halos via DPP.
__device__ __forceinline__ void l96_seg(const v2* __restrict__ a, v2* __restrict__ k) {
    const v2 hm2 = dpp_prev(a[LP - 2]);
    const v2 hm1 = dpp_prev(a[LP - 1]);
    const v2 hp1 = dpp_next(a[0]);
    const v2 F = sp(8.0f);
    k[0] = vfma(a[1] - hm2, hm1, F - a[0]);
    k[1] = vfma(a[2] - hm1, a[0], F - a[1]);
#pragma unroll
    for (int j = 2; j < LP - 1; ++j)
        k[j] = vfma(a[j + 1] - a[j - 2], a[j - 1], F - a[j]);
    k[LP - 1] = vfma(hp1 - a[LP - 3], a[LP - 2], F - a[LP - 1]);
}

// In-place variant: halos captured first, then rolling window (SSA renames).
__device__ __forceinline__ void l96_seg_inplace(v2* a) {
    const v2 hp1 = dpp_next(a[0]);
    v2 prev2 = dpp_prev(a[LP - 2]);
    v2 prev1 = dpp_prev(a[LP - 1]);
    const v2 F = sp(8.0f);
#pragma unroll
    for (int j = 0; j < LP; ++j) {
        const v2 ip1 = (j < LP - 1) ? a[j + 1] : hp1;
        const v2 old = a[j];
        a[j] = vfma(ip1 - prev2, prev1, F - old);
        prev2 = prev1;
        prev1 = old;
    }
}

// Round-2/5 RK4(3/8) flow, bit-identical fmaf sequence per element, with two
// rows packed per thread as <2 x float> so LLVM selects VOP3P packed-fp32
// (v_pk_fma_f32 etc). Rounds 2-5 established dur = VALU-instrs x 4 cyc on
// gfx950 regardless of liveness/occupancy/VGPR knobs; packing halves the
// instruction count per element (24.2 -> 12.7 slots/elem) IF pk ops cost one
// slot — this kernel is the discriminating experiment.
__global__ void __launch_bounds__(256)
lorenz96_rk4_kernel(const float* __restrict__ in,
                    float* __restrict__ out,
                    int batch) {
    const int gtid = blockIdx.x * blockDim.x + threadIdx.x;
    const int rp  = gtid >> 2;   // row pair index
    const int sub = gtid & 3;    // quad lane: elements [sub*10, sub*10+10)
    if (rp >= (batch >> 1)) return;

    const float* __restrict__ r0 = in + (size_t)(2 * rp) * 40 + sub * LP;
    const float* __restrict__ r1 = r0 + 40;

    v2 X[LP];  // x  -> b  -> a4 -> k4 -> x'
    v2 W[LP];  // k1 -> u  -> a3 -> k3
    v2 A[LP];  // acc
    v2 S[LP];  // a2 -> k2
#pragma unroll
    for (int j = 0; j < LP; ++j) { X[j].x = r0[j]; X[j].y = r1[j]; }  // contiguous -> dwordx4

    const float dt  = 0.01f;
    const float dt3 = dt * (1.0f / 3.0f);  // dt/3
    const float dt8 = dt * 0.125f;         // dt/8
    const v2 vdt3 = sp(dt3), vndt3 = sp(-dt3), vdt = sp(dt), vndt = sp(-dt);
    const v2 vdt8 = sp(dt8), vth = sp(3.0f * dt8), v3 = sp(3.0f), v0375 = sp(0.375f);

#pragma unroll 1
    for (int s = 0; s < NSTEP; ++s) {
        // k1 = f(x)
        l96_seg(X, W);

        // u = dt/3*k1 ; acc = x + 0.375*u ; a2 = x + u
#pragma unroll
        for (int i = 0; i < LP; ++i) {
            W[i] = vdt3 * W[i];
            A[i] = vfma(v0375, W[i], X[i]);
            S[i] = X[i] + W[i];
        }

        // k2 = f(a2)
        l96_seg_inplace(S);

        // acc += 3dt/8*k2 ; a3 = (x-u) + dt*k2 ; b = (x+3u) - dt*k2
#pragma unroll
        for (int i = 0; i < LP; ++i) {
            A[i] = vfma(vth, S[i], A[i]);
            const v2 t = X[i] - W[i];
            X[i] = vfma(vndt, S[i], vfma(v3, W[i], X[i]));  // b
            W[i] = vfma(vdt, S[i], t);                      // a3
        }

        // k3 = f(a3)
        l96_seg_inplace(W);

        // acc += 3dt/8*k3 ; a4 = b + dt*k3
#pragma unroll
        for (int i = 0; i < LP; ++i) {
            A[i] = vfma(vth, W[i], A[i]);
            X[i] = vfma(vdt, W[i], X[i]);
        }

        // k4 = f(a4)
        l96_seg_inplace(X);

        // x' = acc + dt/8*k4
#pragma unroll
        for (int i = 0; i < LP; ++i) X[i] = vfma(vdt8, X[i], A[i]);
    }

    float* __restrict__ o0 = out + (size_t)(2 * rp) * 40 + sub * LP;
    float* __restrict__ o1 = o0 + 40;
#pragma unroll
    for (int j = 0; j < LP; ++j) { o0[j] = X[j].x; o1[j] = X[j].y; }
}

extern "C" void kernel_launch(void* const* d_in, const int* in_sizes, int n_in,
                              void* d_out, int out_size, void* d_ws, size_t ws_size,
                              hipStream_t stream) {
    const float* x = (const float*)d_in[0];
    float* out = (float*)d_out;
    const int batch = in_sizes[0] / 40;              // 262144 (even)
    const int block = 256;
    const long long threads = (long long)(batch / 2) * 4;  // 4 lanes per row-pair
    const int grid = (int)((threads + block - 1) / block);
    lorenz96_rk4_kernel<<<grid, block, 0, stream>>>(x, out, batch);
}